// Round 8
// baseline (417.479 us; speedup 1.0000x reference)
//
#include <hip/hip_runtime.h>
#include <stdint.h>

#define N_NODES 4096
#define F_DIM   64
#define LRELU_ALPHA 0.2f

typedef _Float16 f16;
typedef __attribute__((ext_vector_type(8))) _Float16 half8;  // MFMA f16 A/B frag (4 VGPRs)
typedef __attribute__((ext_vector_type(4))) float f32x4;     // MFMA C/D frag

// ---------------------------------------------------------------------------
// Kernel 1: Wh = h@W (fp32 VALU); ei=Wh·a1, ej=Wh·a2; wh16[b][f][n] = (f16)Wh
// (transposed via LDS for coalesced stores); blockmax[blk] = max ej over the
// block's 16 rows (plain store — no atomics, no memset needed).
// grid 1024 x 256 (4 blocks/CU); wave = 4 rows.
// ---------------------------------------------------------------------------
__global__ __launch_bounds__(256) void gat_prep(
    const float* __restrict__ h, const float* __restrict__ W,
    const float* __restrict__ a, float* __restrict__ ei,
    float* __restrict__ ej, f16* __restrict__ wh16,
    float* __restrict__ blockmax)
{
  __shared__ float sh_h[4][F_DIM];
  __shared__ f16 tile[F_DIM][16];   // [f][local n]
  __shared__ float wmax[4];
  const int t = threadIdx.x, w = t >> 6, lane = t & 63;
  const int n0 = blockIdx.x * 16;       // global row base (0..16383)
  const int b  = n0 >> 12;
  const int nl0 = n0 & (N_NODES - 1);   // row base within batch

  float wcol[F_DIM];
#pragma unroll
  for (int k = 0; k < F_DIM; ++k) wcol[k] = W[k * F_DIM + lane];
  const float a1 = a[lane], a2 = a[F_DIM + lane];

  float runmax = -3e38f;
  for (int r = 0; r < 4; ++r) {
    const int loc = w * 4 + r;
    const int n = n0 + loc;
    const float hv = h[(size_t)n * F_DIM + lane];
    sh_h[w][lane] = hv;                       // same-wave LDS write->read (in-order pipe)
    float wh = 0.f;
#pragma unroll
    for (int k = 0; k < F_DIM; k += 4) {
      const float4 hb = *(const float4*)(&sh_h[w][k]);
      wh = fmaf(hb.x, wcol[k + 0], wh);
      wh = fmaf(hb.y, wcol[k + 1], wh);
      wh = fmaf(hb.z, wcol[k + 2], wh);
      wh = fmaf(hb.w, wcol[k + 3], wh);
    }
    float s1 = wh * a1, s2 = wh * a2;
#pragma unroll
    for (int off = 32; off; off >>= 1) {
      s1 += __shfl_xor(s1, off);
      s2 += __shfl_xor(s2, off);
    }
    if (lane == 0) { ei[n] = s1; ej[n] = s2; }
    runmax = fmaxf(runmax, s2);               // s2 identical on all lanes
    tile[lane][loc] = (f16)wh;                // f = lane
  }
  if (lane == 0) wmax[w] = runmax;
  __syncthreads();

  // coalesced f16 store: thread t -> f = t>>2, 8B chunk part = t&3
  {
    const int f = t >> 2, part = t & 3;
    *(uint2*)(wh16 + ((size_t)(b * F_DIM + f)) * N_NODES + nl0 + part * 4) =
        *(const uint2*)(&tile[f][part * 4]);
  }
  if (t == 0)
    blockmax[blockIdx.x] =
        fmaxf(fmaxf(wmax[0], wmax[1]), fmaxf(wmax[2], wmax[3]));
}

// ---------------------------------------------------------------------------
// Kernel 2: fused masked-softmax attention + PV (f16 MFMA) + ELU, direct out.
// block = (b, 16-row i-tile), 512 threads = 8 waves; wave w sweeps j in
// [w*512, (w+1)*512). grid 1024 -> 4 blocks/CU = 32 waves/CU (occupancy-
// driven: round-1 was latency-bound at 42%). In-block LDS reduction merges
// the 8 j-partials; no global accumulators, no atomics.
// Range control: p' = exp(leaky(e) - bnd), bnd = leaky(ei + maxej_batch)
// >= row max (leaky monotone) -> p' in (0,1], f16-safe; shift cancels in
// num/den. A-frag: A[m=lane&15][k=quad*8+x]; B-frag: B[k][n=lane&15];
// C/D: row=quad*4+reg, col=lane&15 (HW-verified m89/m91).
// ---------------------------------------------------------------------------
__global__ __launch_bounds__(512, 6) void gat_attn(
    const int* __restrict__ adj, const float* __restrict__ ei,
    const float* __restrict__ ej, const f16* __restrict__ wh16,
    const float* __restrict__ blockmax, float* __restrict__ out)
{
  __shared__ float num_lds[8][16][F_DIM];   // 32 KB
  __shared__ float den_lds[8][16];          // 512 B

  const int t = threadIdx.x, w = t >> 6, lane = t & 63;
  const int quad = lane >> 4, m = lane & 15;
  const int b  = blockIdx.x >> 8;            // 256 i-tiles per batch
  const int i0 = (blockIdx.x & 255) * 16;
  const int i  = i0 + m;
  const int rowg = b * N_NODES + i;

  // per-batch max(ej): reduce 256 plain-stored per-block maxima (L2-hot)
  float maxej;
  {
    const float4 v = *(const float4*)(blockmax + b * 256 + lane * 4);
    maxej = fmaxf(fmaxf(v.x, v.y), fmaxf(v.z, v.w));
#pragma unroll
    for (int off = 32; off; off >>= 1)
      maxej = fmaxf(maxej, __shfl_xor(maxej, off));
  }

  const float ei_s = ei[rowg];
  float bnd = ei_s + maxej;
  bnd = fmaxf(bnd, LRELU_ALPHA * bnd);       // leaky(ei + maxej) >= row max logit

  const float* ejb     = ej + b * N_NODES;
  const int*   adj_row = adj + (size_t)rowg * N_NODES;
  const f16*   whb     = wh16 + ((size_t)(b * F_DIM + m)) * N_NODES;

  f32x4 acc[4] = {{0.f,0.f,0.f,0.f},{0.f,0.f,0.f,0.f},
                  {0.f,0.f,0.f,0.f},{0.f,0.f,0.f,0.f}};
  float den = 0.f;
  const int jbase = w * (N_NODES / 8);       // this wave's 512-j window

  for (int jc = 0; jc < 16; ++jc) {
    const int jk = jbase + jc * 32 + quad * 8;

    float ejA[8];
    *(float4*)(&ejA[0]) = *(const float4*)(ejb + jk);
    *(float4*)(&ejA[4]) = *(const float4*)(ejb + jk + 4);
    int adA[8];
    *(int4*)(&adA[0]) = *(const int4*)(adj_row + jk);
    *(int4*)(&adA[4]) = *(const int4*)(adj_row + jk + 4);

    half8 bf[4];
#pragma unroll
    for (int fc = 0; fc < 4; ++fc)
      bf[fc] = *(const half8*)(whb + (size_t)(fc * 16) * N_NODES + jk);

    half8 pa;
#pragma unroll
    for (int x = 0; x < 8; ++x) {
      float e = ei_s + ejA[x];
      e = fmaxf(e, LRELU_ALPHA * e);
      const float p = (adA[x] > 0) ? __expf(e - bnd) : 0.f;
      pa[x] = (f16)p;
      den += (float)pa[x];     // accumulate the SAME quantized value MFMA sees
    }

#pragma unroll
    for (int fc = 0; fc < 4; ++fc)
      acc[fc] = __builtin_amdgcn_mfma_f32_16x16x32_f16(pa, bf[fc], acc[fc], 0, 0, 0);
  }

  // den: lanes sharing a row (same lane&15) live 16 apart
  den += __shfl_xor(den, 16);
  den += __shfl_xor(den, 32);
  if (lane < 16) den_lds[w][lane] = den;

#pragma unroll
  for (int fc = 0; fc < 4; ++fc)
#pragma unroll
    for (int rg = 0; rg < 4; ++rg)
      num_lds[w][quad * 4 + rg][fc * 16 + m] = acc[fc][rg];
  __syncthreads();

  // merge 8 wave-partials, divide, ELU, coalesced store (1024 outs, 512 thr)
#pragma unroll
  for (int k = 0; k < 2; ++k) {
    const int idx = k * 512 + t;
    const int il = idx >> 6, f = idx & 63;
    float num = 0.f, d = 0.f;
#pragma unroll
    for (int ww = 0; ww < 8; ++ww) {
      num += num_lds[ww][il][f];
      d   += den_lds[ww][il];
    }
    float v = (d > 0.f) ? (num / d) : 0.f;
    v = (v > 0.f) ? v : expm1f(v);
    out[((size_t)(b * N_NODES + i0 + il)) * F_DIM + f] = v;
  }
}

extern "C" void kernel_launch(void* const* d_in, const int* in_sizes, int n_in,
                              void* d_out, int out_size, void* d_ws, size_t ws_size,
                              hipStream_t stream) {
  const float* h   = (const float*)d_in[0];
  const int*   adj = (const int*)d_in[1];
  const float* W   = (const float*)d_in[2];
  const float* a   = (const float*)d_in[3];
  float* out = (float*)d_out;

  char* ws = (char*)d_ws;
  // Workspace (2.14 MB total — well inside the 4.33 MB proven in round 1):
  // [0,       +64 KB)  ei
  // [65536,   +64 KB)  ej
  // [131072,  +4 KB)   blockmax (1024 floats, fully written by gat_prep)
  // [135168,  +2 MB)   wh16
  float* ei       = (float*)ws;
  float* ej       = (float*)(ws + 65536);
  float* blockmax = (float*)(ws + 131072);
  f16*   wh16     = (f16*)(ws + 135168);

  hipLaunchKernelGGL(gat_prep, dim3(1024), dim3(256), 0, stream,
                     h, W, a, ei, ej, wh16, blockmax);
  hipLaunchKernelGGL(gat_attn, dim3(1024), dim3(512), 0, stream,
                     adj, ei, ej, wh16, blockmax, out);
}

// Round 10
// 411.814 us; speedup vs baseline: 1.0138x; 1.0138x over previous
//
#include <hip/hip_runtime.h>
#include <stdint.h>

#define N_NODES 4096
#define F_DIM   64
#define LRELU_ALPHA 0.2f

typedef _Float16 f16;
typedef __attribute__((ext_vector_type(8))) _Float16 half8;  // MFMA f16 A/B frag (4 VGPRs)
typedef __attribute__((ext_vector_type(4))) float f32x4;     // MFMA C/D frag

// ---------------------------------------------------------------------------
// Kernel 1: Wh = h@W (fp32 VALU); ei=Wh·a1, ej=Wh·a2; wh16[b][f][n] = (f16)Wh
// (transposed via LDS for coalesced stores); blockmax[blk] = max ej over the
// block's 16 rows (plain store — no atomics, no memset needed).
// grid 1024 x 256 (4 blocks/CU); wave = 4 rows.
// [unchanged from the R4/R8 proven-pass anchor]
// ---------------------------------------------------------------------------
__global__ __launch_bounds__(256) void gat_prep(
    const float* __restrict__ h, const float* __restrict__ W,
    const float* __restrict__ a, float* __restrict__ ei,
    float* __restrict__ ej, f16* __restrict__ wh16,
    float* __restrict__ blockmax)
{
  __shared__ float sh_h[4][F_DIM];
  __shared__ f16 tile[F_DIM][16];   // [f][local n]
  __shared__ float wmax[4];
  const int t = threadIdx.x, w = t >> 6, lane = t & 63;
  const int n0 = blockIdx.x * 16;       // global row base (0..16383)
  const int b  = n0 >> 12;
  const int nl0 = n0 & (N_NODES - 1);   // row base within batch

  float wcol[F_DIM];
#pragma unroll
  for (int k = 0; k < F_DIM; ++k) wcol[k] = W[k * F_DIM + lane];
  const float a1 = a[lane], a2 = a[F_DIM + lane];

  float runmax = -3e38f;
  for (int r = 0; r < 4; ++r) {
    const int loc = w * 4 + r;
    const int n = n0 + loc;
    const float hv = h[(size_t)n * F_DIM + lane];
    sh_h[w][lane] = hv;                       // same-wave LDS write->read (in-order pipe)
    float wh = 0.f;
#pragma unroll
    for (int k = 0; k < F_DIM; k += 4) {
      const float4 hb = *(const float4*)(&sh_h[w][k]);
      wh = fmaf(hb.x, wcol[k + 0], wh);
      wh = fmaf(hb.y, wcol[k + 1], wh);
      wh = fmaf(hb.z, wcol[k + 2], wh);
      wh = fmaf(hb.w, wcol[k + 3], wh);
    }
    float s1 = wh * a1, s2 = wh * a2;
#pragma unroll
    for (int off = 32; off; off >>= 1) {
      s1 += __shfl_xor(s1, off);
      s2 += __shfl_xor(s2, off);
    }
    if (lane == 0) { ei[n] = s1; ej[n] = s2; }
    runmax = fmaxf(runmax, s2);               // s2 identical on all lanes
    tile[lane][loc] = (f16)wh;                // f = lane
  }
  if (lane == 0) wmax[w] = runmax;
  __syncthreads();

  // coalesced f16 store: thread t -> f = t>>2, 8B chunk part = t&3
  {
    const int f = t >> 2, part = t & 3;
    *(uint2*)(wh16 + ((size_t)(b * F_DIM + f)) * N_NODES + nl0 + part * 4) =
        *(const uint2*)(&tile[f][part * 4]);
  }
  if (t == 0)
    blockmax[blockIdx.x] =
        fmaxf(fmaxf(wmax[0], wmax[1]), fmaxf(wmax[2], wmax[3]));
}

// ---------------------------------------------------------------------------
// Kernel 2: fused masked-softmax attention + PV (f16 MFMA) + ELU, direct out.
// block = (b, 16-row i-tile), 512 threads = 8 waves; wave w sweeps j in
// [w*512, (w+1)*512). In-block LDS reduction merges the 8 j-partials.
// SINGLE delta vs the R4/R8 proven anchor: depth-1 software prefetch of the
// adj stream (the only cold-HBM stream) with plain int4 loads — iter n+1's
// two 16-B adj loads issue before iter n's exp/MFMA work, overlapping the
// ~900-cycle HBM latency the R8 profile shows is exposed. Everything else
// (prep, exp path, loads, reduction) is byte-identical to the anchor.
// Range control: p' = exp(leaky(e) - bnd), bnd = leaky(ei + maxej_batch)
// >= row max (leaky monotone) -> p' in (0,1], f16-safe; shift cancels in
// num/den. A-frag: A[m=lane&15][k=quad*8+x]; B-frag: B[k][n=lane&15];
// C/D: row=quad*4+reg, col=lane&15 (HW-verified m89/m91).
// ---------------------------------------------------------------------------
__global__ __launch_bounds__(512, 6) void gat_attn(
    const int* __restrict__ adj, const float* __restrict__ ei,
    const float* __restrict__ ej, const f16* __restrict__ wh16,
    const float* __restrict__ blockmax, float* __restrict__ out)
{
  __shared__ float num_lds[8][16][F_DIM];   // 32 KB
  __shared__ float den_lds[8][16];          // 512 B

  const int t = threadIdx.x, w = t >> 6, lane = t & 63;
  const int quad = lane >> 4, m = lane & 15;
  const int b  = blockIdx.x >> 8;            // 256 i-tiles per batch
  const int i0 = (blockIdx.x & 255) * 16;
  const int i  = i0 + m;
  const int rowg = b * N_NODES + i;

  // per-batch max(ej): reduce 256 plain-stored per-block maxima (L2-hot)
  float maxej;
  {
    const float4 v = *(const float4*)(blockmax + b * 256 + lane * 4);
    maxej = fmaxf(fmaxf(v.x, v.y), fmaxf(v.z, v.w));
#pragma unroll
    for (int off = 32; off; off >>= 1)
      maxej = fmaxf(maxej, __shfl_xor(maxej, off));
  }

  const float ei_s = ei[rowg];
  float bnd = ei_s + maxej;
  bnd = fmaxf(bnd, LRELU_ALPHA * bnd);       // leaky(ei + maxej) >= row max logit

  const float* ejb     = ej + b * N_NODES;
  const int*   adj_row = adj + (size_t)rowg * N_NODES;
  const f16*   whb     = wh16 + ((size_t)(b * F_DIM + m)) * N_NODES;

  f32x4 acc[4] = {{0.f,0.f,0.f,0.f},{0.f,0.f,0.f,0.f},
                  {0.f,0.f,0.f,0.f},{0.f,0.f,0.f,0.f}};
  float den = 0.f;
  const int jbase = w * (N_NODES / 8);       // this wave's 512-j window

  // prologue: iter-0 adj loads
  int4 adn0 = *(const int4*)(adj_row + jbase + quad * 8);
  int4 adn1 = *(const int4*)(adj_row + jbase + quad * 8 + 4);

  for (int jc = 0; jc < 16; ++jc) {
    const int jk = jbase + jc * 32 + quad * 8;
    const int4 ad0 = adn0, ad1 = adn1;

    // issue next iter's adj loads NOW (the only cold-HBM stream)
    if (jc < 15) {
      adn0 = *(const int4*)(adj_row + jk + 32);
      adn1 = *(const int4*)(adj_row + jk + 36);
    }

    float ejA[8];
    *(float4*)(&ejA[0]) = *(const float4*)(ejb + jk);
    *(float4*)(&ejA[4]) = *(const float4*)(ejb + jk + 4);
    int adA[8] = {ad0.x, ad0.y, ad0.z, ad0.w, ad1.x, ad1.y, ad1.z, ad1.w};

    half8 bf[4];
#pragma unroll
    for (int fc = 0; fc < 4; ++fc)
      bf[fc] = *(const half8*)(whb + (size_t)(fc * 16) * N_NODES + jk);

    half8 pa;
#pragma unroll
    for (int x = 0; x < 8; ++x) {
      float e = ei_s + ejA[x];
      e = fmaxf(e, LRELU_ALPHA * e);
      const float p = (adA[x] > 0) ? __expf(e - bnd) : 0.f;
      pa[x] = (f16)p;
      den += (float)pa[x];     // accumulate the SAME quantized value MFMA sees
    }

#pragma unroll
    for (int fc = 0; fc < 4; ++fc)
      acc[fc] = __builtin_amdgcn_mfma_f32_16x16x32_f16(pa, bf[fc], acc[fc], 0, 0, 0);
  }

  // den: lanes sharing a row (same lane&15) live 16 apart
  den += __shfl_xor(den, 16);
  den += __shfl_xor(den, 32);
  if (lane < 16) den_lds[w][lane] = den;

#pragma unroll
  for (int fc = 0; fc < 4; ++fc)
#pragma unroll
    for (int rg = 0; rg < 4; ++rg)
      num_lds[w][quad * 4 + rg][fc * 16 + m] = acc[fc][rg];
  __syncthreads();

  // merge 8 wave-partials, divide, ELU, coalesced store (1024 outs, 512 thr)
#pragma unroll
  for (int k = 0; k < 2; ++k) {
    const int idx = k * 512 + t;
    const int il = idx >> 6, f = idx & 63;
    float num = 0.f, d = 0.f;
#pragma unroll
    for (int ww = 0; ww < 8; ++ww) {
      num += num_lds[ww][il][f];
      d   += den_lds[ww][il];
    }
    float v = (d > 0.f) ? (num / d) : 0.f;
    v = (v > 0.f) ? v : expm1f(v);
    out[((size_t)(b * N_NODES + i0 + il)) * F_DIM + f] = v;
  }
}

extern "C" void kernel_launch(void* const* d_in, const int* in_sizes, int n_in,
                              void* d_out, int out_size, void* d_ws, size_t ws_size,
                              hipStream_t stream) {
  const float* h   = (const float*)d_in[0];
  const int*   adj = (const int*)d_in[1];
  const float* W   = (const float*)d_in[2];
  const float* a   = (const float*)d_in[3];
  float* out = (float*)d_out;

  char* ws = (char*)d_ws;
  // Workspace (2.14 MB):
  // [0,       +64 KB)  ei
  // [65536,   +64 KB)  ej
  // [131072,  +4 KB)   blockmax (1024 floats, fully written by gat_prep)
  // [135168,  +2 MB)   wh16
  float* ei       = (float*)ws;
  float* ej       = (float*)(ws + 65536);
  float* blockmax = (float*)(ws + 131072);
  f16*   wh16     = (f16*)(ws + 135168);

  hipLaunchKernelGGL(gat_prep, dim3(1024), dim3(256), 0, stream,
                     h, W, a, ei, ej, wh16, blockmax);
  hipLaunchKernelGGL(gat_attn, dim3(1024), dim3(512), 0, stream,
                     adj, ei, ej, wh16, blockmax, out);
}